// Round 1
// baseline (857.664 us; speedup 1.0000x reference)
//
#include <hip/hip_runtime.h>
#include <math.h>

// Problem constants: B=64, D=512, H=HID=512 -> M = B*D = 32768, K = N = 512.
#define MM 32768
#define KK 512
#define NN 512
#define BM 128
#define BN 128
#define BK 32

typedef float  f32x4  __attribute__((ext_vector_type(4)));
typedef __bf16 bf16x8 __attribute__((ext_vector_type(8)));
typedef unsigned short u16x8 __attribute__((ext_vector_type(8)));

__device__ __forceinline__ unsigned short f2bf(float f) {
    union { float f; unsigned int u; } v; v.f = f;
    unsigned int r = v.u + 0x7fffu + ((v.u >> 16) & 1u);  // round-to-nearest-even
    return (unsigned short)(r >> 16);
}

__device__ __forceinline__ void gl_lds16(const void* g, void* l) {
    __builtin_amdgcn_global_load_lds((const __attribute__((address_space(1))) void*)g,
                                     (__attribute__((address_space(3))) void*)l,
                                     16, 0, 0);
}

// ---------------------------------------------------------------------------
// fsum = fea1+fea2+fea3+fea4, cast to bf16.  8 elements / thread.
// ---------------------------------------------------------------------------
__global__ __launch_bounds__(256)
void fsum_cast(const float* __restrict__ f1, const float* __restrict__ f2,
               const float* __restrict__ f3, const float* __restrict__ f4,
               unsigned short* __restrict__ out)
{
    const long i = ((long)blockIdx.x * 256 + threadIdx.x) * 8;
    f32x4 s0 = *(const f32x4*)(f1 + i);
    f32x4 s1 = *(const f32x4*)(f1 + i + 4);
    s0 += *(const f32x4*)(f2 + i);  s1 += *(const f32x4*)(f2 + i + 4);
    s0 += *(const f32x4*)(f3 + i);  s1 += *(const f32x4*)(f3 + i + 4);
    s0 += *(const f32x4*)(f4 + i);  s1 += *(const f32x4*)(f4 + i + 4);
    u16x8 o;
    o[0] = f2bf(s0[0]); o[1] = f2bf(s0[1]); o[2] = f2bf(s0[2]); o[3] = f2bf(s0[3]);
    o[4] = f2bf(s1[0]); o[5] = f2bf(s1[1]); o[6] = f2bf(s1[2]); o[7] = f2bf(s1[3]);
    *(u16x8*)(out + i) = o;
}

// ---------------------------------------------------------------------------
// Weight prep: transpose to (N,K) row-major bf16.
//   z = 0     : WgT[n][k]    = 0.25 * W_gcn[k][n]        (0.25 = Ahat folded in)
//   z = 1..4  : W1effT[n][k] = sum_b W1_i[b*512 + k][n]  (z concat collapse)
//   z = 5..8  : W2T[n][k]    = W2_i[k][n]
// ---------------------------------------------------------------------------
struct WArgs {
    const float* src[9];
    unsigned short* dst[9];
};

__global__ __launch_bounds__(256)
void wprep(WArgs a)
{
    __shared__ float t[32][33];
    const int z  = blockIdx.z;
    const float* __restrict__ src = a.src[z];
    unsigned short* __restrict__ dst = a.dst[z];
    const int k0 = blockIdx.x * 32;
    const int n0 = blockIdx.y * 32;
    const int tx = threadIdx.x;
    for (int kk = threadIdx.y; kk < 32; kk += 8) {
        float v = src[(long)(k0 + kk) * 512 + n0 + tx];
        if (z >= 1 && z <= 4) {
            v += src[(long)(512  + k0 + kk) * 512 + n0 + tx];
            v += src[(long)(1024 + k0 + kk) * 512 + n0 + tx];
            v += src[(long)(1536 + k0 + kk) * 512 + n0 + tx];
        }
        if (z == 0) v *= 0.25f;
        t[kk][tx] = v;
    }
    __syncthreads();
    for (int nn = threadIdx.y; nn < 32; nn += 8) {
        dst[(long)(n0 + nn) * 512 + k0 + tx] = f2bf(t[tx][nn]);
    }
}

// ---------------------------------------------------------------------------
// GEMM: C(M x N) = A(M x K, bf16) @ Bt(N x K, bf16)^T, + bias epilogue.
// MODE 0: store bf16(v + bias)                      (s stage)
// MODE 1: store bf16(relu(v + bias))                (h stage)
// MODE 2: store fp32 sigmoid(v + bias) * fea        (output stage)
// 128x128 tile, BK=32, 4 waves (2x2), 4x4 16x16x32 MFMA tiles per wave.
// Staging: global_load_lds width 16; waves 0/1 stage A rows 0-63/64-127,
// waves 2/3 stage Bt rows likewise. LDS layout [row][BK] (64 B rows).
// ---------------------------------------------------------------------------
template<int MODE>
__global__ __launch_bounds__(256)
void gemm_ep(const unsigned short* __restrict__ A,
             const unsigned short* __restrict__ Bt,
             const float* __restrict__ bias,
             const float* __restrict__ fea,
             void* __restrict__ out)
{
    __shared__ unsigned short As[BM * BK];   // 8 KB
    __shared__ unsigned short Bs[BN * BK];   // 8 KB

    const int tid  = threadIdx.x;
    const int lane = tid & 63;
    const int wave = tid >> 6;
    const int m0 = blockIdx.x * BM;
    const int n0 = blockIdx.y * BN;

    // staging role (wave-uniform)
    const bool isA = (wave < 2);
    const int rowbase = (wave & 1) * 64;
    const unsigned short* gsrc = isA ? A : Bt;
    unsigned short* ldst = isA ? As : Bs;
    const int r  = lane >> 2;   // 0..15 : row within 16-row chunk
    const int cb = lane & 3;    // 0..3  : 16B segment within 64B row
    const long grow0 = (isA ? (long)m0 : (long)n0) + rowbase;
    const unsigned short* gbase0 = gsrc + grow0 * KK + cb * 8;
    unsigned short* lbase = ldst + rowbase * BK;

    // fragment geometry: A[m=lane&15][k=(lane>>4)*8+j], B mirrored.
    const int frow = lane & 15;
    const int fk   = (lane >> 4) * 8;
    const int wrow = wave >> 1;
    const int wcol = wave & 1;

    f32x4 acc[4][4] = {};

    for (int ks = 0; ks < KK / BK; ++ks) {
        const unsigned short* gb = gbase0 + ks * BK;
        #pragma unroll
        for (int c = 0; c < 4; ++c) {
            gl_lds16(gb + (long)(c * 16 + r) * KK, lbase + c * 16 * BK);
        }
        __syncthreads();   // drains vmcnt for the async LDS loads

        bf16x8 afr[4], bfr[4];
        #pragma unroll
        for (int i = 0; i < 4; ++i)
            afr[i] = *(const bf16x8*)(As + (wrow * 64 + i * 16 + frow) * BK + fk);
        #pragma unroll
        for (int j = 0; j < 4; ++j)
            bfr[j] = *(const bf16x8*)(Bs + (wcol * 64 + j * 16 + frow) * BK + fk);

        #pragma unroll
        for (int i = 0; i < 4; ++i)
            #pragma unroll
            for (int j = 0; j < 4; ++j)
                acc[i][j] = __builtin_amdgcn_mfma_f32_16x16x32_bf16(
                    afr[i], bfr[j], acc[i][j], 0, 0, 0);
        __syncthreads();   // protect LDS from next iteration's staging
    }

    // epilogue: C/D layout col=lane&15, row=(lane>>4)*4+reg  [m89-verified]
    const int cq = (lane >> 4) * 4;
    const int cc = lane & 15;
    #pragma unroll
    for (int j = 0; j < 4; ++j) {
        const int col = n0 + wcol * 64 + j * 16 + cc;
        const float bv = bias[col];
        #pragma unroll
        for (int i = 0; i < 4; ++i) {
            #pragma unroll
            for (int rr = 0; rr < 4; ++rr) {
                const int row = m0 + wrow * 64 + i * 16 + cq + rr;
                float v = acc[i][j][rr] + bv;
                if (MODE == 0) {
                    ((unsigned short*)out)[(long)row * NN + col] = f2bf(v);
                } else if (MODE == 1) {
                    ((unsigned short*)out)[(long)row * NN + col] = f2bf(fmaxf(v, 0.0f));
                } else {
                    const float g = 1.0f / (1.0f + __expf(-v));
                    ((float*)out)[(long)row * NN + col] =
                        g * fea[(long)row * NN + col];
                }
            }
        }
    }
}

// ---------------------------------------------------------------------------
extern "C" void kernel_launch(void* const* d_in, const int* in_sizes, int n_in,
                              void* d_out, int out_size, void* d_ws, size_t ws_size,
                              hipStream_t stream)
{
    (void)in_sizes; (void)n_in; (void)out_size; (void)ws_size;

    const float* fea[4] = {(const float*)d_in[0], (const float*)d_in[1],
                           (const float*)d_in[2], (const float*)d_in[3]};
    const float* W_gcn = (const float*)d_in[4];
    const float* b_gcn = (const float*)d_in[5];
    const float *W1[4], *b1[4], *W2[4], *b2[4];
    for (int i = 0; i < 4; ++i) {
        W1[i] = (const float*)d_in[6 + 4 * i];
        b1[i] = (const float*)d_in[7 + 4 * i];
        W2[i] = (const float*)d_in[8 + 4 * i];
        b2[i] = (const float*)d_in[9 + 4 * i];
    }

    // workspace layout (bytes): [0,32M) fsum (reused as h), [32M,64M) s,
    // [64M, 64M+4.5M) 9 transposed bf16 weight matrices (512x512 each).
    char* ws = (char*)d_ws;
    unsigned short* fsum_h = (unsigned short*)ws;
    unsigned short* s_buf  = (unsigned short*)(ws + (size_t)33554432);
    unsigned short* wbuf   = (unsigned short*)(ws + (size_t)67108864);
    unsigned short* WgT = wbuf;
    unsigned short *W1T[4], *W2T[4];
    for (int i = 0; i < 4; ++i) {
        W1T[i] = wbuf + (size_t)(1 + i) * 262144;
        W2T[i] = wbuf + (size_t)(5 + i) * 262144;
    }

    fsum_cast<<<8192, 256, 0, stream>>>(fea[0], fea[1], fea[2], fea[3], fsum_h);

    WArgs wa;
    wa.src[0] = W_gcn; wa.dst[0] = WgT;
    for (int i = 0; i < 4; ++i) { wa.src[1 + i] = W1[i]; wa.dst[1 + i] = W1T[i]; }
    for (int i = 0; i < 4; ++i) { wa.src[5 + i] = W2[i]; wa.dst[5 + i] = W2T[i]; }
    wprep<<<dim3(16, 16, 9), dim3(32, 8), 0, stream>>>(wa);

    const dim3 ggrid(MM / BM, NN / BN);  // 256 x 4
    gemm_ep<0><<<ggrid, 256, 0, stream>>>(fsum_h, WgT, b_gcn, nullptr, s_buf);

    float* outp = (float*)d_out;
    for (int i = 0; i < 4; ++i) {
        gemm_ep<1><<<ggrid, 256, 0, stream>>>(s_buf, W1T[i], b1[i], nullptr, fsum_h);
        gemm_ep<2><<<ggrid, 256, 0, stream>>>(fsum_h, W2T[i], b2[i], fea[i],
                                              outp + (size_t)i * MM * NN);
    }
}